// Round 10
// baseline (256.218 us; speedup 1.0000x reference)
//
#include <hip/hip_runtime.h>

#define N_ROWS 32768
#define DIM    256
#define K_EMB  2048
#define OUT_ZQ_SIZE (N_ROWS * DIM)
#define DELTA  4e-4f
#define CAP    32

typedef short s16x8 __attribute__((ext_vector_type(8)));
typedef float f32x4 __attribute__((ext_vector_type(4)));

// min across each 16-lane DPP row via row_ror 8,4,2,1
__device__ inline float row16_min(float x) {
    int v = __builtin_amdgcn_update_dpp(0, __float_as_int(x), 0x128, 0xf, 0xf, false);
    x = fminf(x, __int_as_float(v));
    v = __builtin_amdgcn_update_dpp(0, __float_as_int(x), 0x124, 0xf, 0xf, false);
    x = fminf(x, __int_as_float(v));
    v = __builtin_amdgcn_update_dpp(0, __float_as_int(x), 0x122, 0xf, 0xf, false);
    x = fminf(x, __int_as_float(v));
    v = __builtin_amdgcn_update_dpp(0, __float_as_int(x), 0x121, 0xf, 0xf, false);
    x = fminf(x, __int_as_float(v));
    return x;
}

// ---------------- fused: f32 -> bf16 (RNE) + numpy-pairwise row sumsq ----------------
__global__ __launch_bounds__(256) void prep(const float* __restrict__ src,
                                            unsigned short* __restrict__ dstb,
                                            float* __restrict__ dst2) {
    const int t = threadIdx.x;
    {
        size_t e0 = (size_t)blockIdx.x * 2048 + (size_t)t * 8;
        const float4* s = (const float4*)(src + e0);
        float4 v0 = s[0], v1 = s[1];
        float f[8] = {v0.x, v0.y, v0.z, v0.w, v1.x, v1.y, v1.z, v1.w};
        unsigned int r[8];
        #pragma unroll
        for (int j = 0; j < 8; j++) {
            unsigned int u = __float_as_uint(f[j]);
            r[j] = (u + 0x7fffu + ((u >> 16) & 1u)) >> 16;
        }
        uint4 o;
        o.x = r[0] | (r[1] << 16);
        o.y = r[2] | (r[3] << 16);
        o.z = r[4] | (r[5] << 16);
        o.w = r[6] | (r[7] << 16);
        *(uint4*)(dstb + e0) = o;
    }
    if (t < 128) {
        int row = blockIdx.x * 8 + (t >> 4);
        int lane = t & 15;
        const float* p = src + (size_t)row * DIM;
        int base = (lane >> 3) * 128 + (lane & 7);
        float r = __fmul_rn(p[base], p[base]);
        #pragma unroll
        for (int i = 1; i < 16; i++) {
            float v = p[base + 8 * i];
            r = __fadd_rn(r, __fmul_rn(v, v));
        }
        r = __fadd_rn(r, __shfl_xor(r, 1, 64));
        r = __fadd_rn(r, __shfl_xor(r, 2, 64));
        r = __fadd_rn(r, __shfl_xor(r, 4, 64));
        r = __fadd_rn(r, __shfl_xor(r, 8, 64));
        if (lane == 0) dst2[row] = r;
    }
}

// ---------------- MFMA screen (quarter-split, low-register, 12 waves/CU) ----------------
// grid 1024 = 256 row-tiles x 4 col-quarters. 256 thr (4 waves).
// Block: 128 rows x 512 cols. Wave w: rows w*32..+31 (rt=2), 64-col kt tiles (ct=4).
// Registers: a[2][8]=64 VGPR + acc[2][4]=32 AGPR -> ~145 total -> 3 waves/SIMD.
__global__ __launch_bounds__(256, 3) void vq_mfma(const unsigned short* __restrict__ zb,
                                                  const unsigned short* __restrict__ eb,
                                                  const float* __restrict__ e2np,
                                                  float2* __restrict__ gcand,
                                                  int* __restrict__ gcount,
                                                  float* __restrict__ growmin) {
    __shared__ __attribute__((aligned(16))) unsigned short Bs[2][8192];  // 2 x 16KB

    const int t = threadIdx.x;
    const int l = t & 63;
    const int w = t >> 6;
    const int tile = blockIdx.x >> 2;
    const int quarter = blockIdx.x & 3;
    const int row0 = tile * 128;
    const int col0 = quarter * 512;
    const int colb = l & 15;
    const int q    = l >> 4;
    const int hi16 = q << 4;
    const int swz  = (colb & 7) << 4;

    // A fragments: rows row0 + w*32 + rt*16 + colb; d = ak*32 + q*8
    s16x8 a[2][8];
    {
        const unsigned short* zbase = zb + (size_t)(row0 + w * 32) * DIM;
        #pragma unroll
        for (int rt = 0; rt < 2; rt++)
            #pragma unroll
            for (int kf = 0; kf < 8; kf++)
                a[rt][kf] = *(const s16x8*)(zbase + (rt * 16 + colb) * DIM + kf * 32 + q * 8);
    }

    // stage one 64col x 128D chunk (16KB) into Bs[buf]
    // LDS layout: [col(64)][chunk-bytes(256)], low-7 of byte swizzled by (col&7)<<4
    auto stage = [&](int buf, int kc0, int dc) {
        char* lbase = (char*)&Bs[buf][0];
        #pragma unroll
        for (int i = 0; i < 4; i++) {
            int s   = (w * 4 + i) * 64 + l;   // 16B slot 0..1023
            int col = s >> 4;                 // 16 slots per 256B col row
            int kk  = (s & 15) << 4;          // byte 0..240
            int ss  = (kk & ~127) | ((kk & 127) ^ ((col & 7) << 4));
            const char* gsrc = (const char*)eb + (size_t)(kc0 + col) * 512 + dc * 256 + ss;
            char* ldst = lbase + (w * 4 + i) * 1024;   // wave-uniform base (+ lane*16 by HW)
            __builtin_amdgcn_global_load_lds(
                (const __attribute__((address_space(1))) unsigned int*)gsrc,
                (__attribute__((address_space(3))) unsigned int*)ldst,
                16, 0, 0);
        }
    };

    float m[8];
    #pragma unroll
    for (int i = 0; i < 8; i++) m[i] = 3.4e38f;

    stage(0, col0, 0);
    __syncthreads();

    f32x4 acc[2][4];

    for (int kt = 0; kt < 8; kt++) {
        const int kcol0 = col0 + kt * 64;

        float e2v[4];
        #pragma unroll
        for (int ct = 0; ct < 4; ct++) e2v[ct] = e2np[kcol0 + ct * 16 + colb];

        #pragma unroll
        for (int rt = 0; rt < 2; rt++)
            #pragma unroll
            for (int ct = 0; ct < 4; ct++)
                acc[rt][ct] = (f32x4){0.f, 0.f, 0.f, 0.f};

        #pragma unroll
        for (int dc = 0; dc < 2; dc++) {
            const int p = kt * 2 + dc;
            const int cur = p & 1;
            if (p < 15) {
                const int pn = p + 1;
                stage(cur ^ 1, col0 + (pn >> 1) * 64, pn & 1);
            }
            const char* rbase = (const char*)&Bs[cur][0];
            #pragma unroll
            for (int kf2 = 0; kf2 < 4; kf2++) {
                const int b0   = kf2 * 64 + hi16;
                const int koff = (b0 & ~127) | ((b0 & 127) ^ swz);
                const int ak   = dc * 4 + kf2;
                #pragma unroll
                for (int ct = 0; ct < 4; ct++) {
                    s16x8 b = *(const s16x8*)(rbase + (ct * 16 + colb) * 256 + koff);
                    acc[0][ct] = __builtin_amdgcn_mfma_f32_16x16x32_bf16(a[0][ak], b, acc[0][ct], 0, 0, 0);
                    acc[1][ct] = __builtin_amdgcn_mfma_f32_16x16x32_bf16(a[1][ak], b, acc[1][ct], 0, 0, 0);
                }
            }
            __syncthreads();   // drains prefetch; protects Bs[cur] overwrite
        }

        // epilogue: s = e2 - 2*dot ; tile-min; running min; push window to GLOBAL
        float tmin[8];
        #pragma unroll
        for (int rt = 0; rt < 2; rt++)
            #pragma unroll
            for (int reg = 0; reg < 4; reg++) {
                int r8 = rt * 4 + reg;
                float t0 = fmaf(-2.f, acc[rt][0][reg], e2v[0]);
                #pragma unroll
                for (int ct = 1; ct < 4; ct++)
                    t0 = fminf(t0, fmaf(-2.f, acc[rt][ct][reg], e2v[ct]));
                tmin[r8] = t0;
                m[r8] = fminf(m[r8], t0);
            }
        #pragma unroll
        for (int r8 = 0; r8 < 8; r8++) {
            float gm  = row16_min(m[r8]);
            float thr = gm + DELTA;
            if (tmin[r8] < thr) {
                int rt = r8 >> 2, reg = r8 & 3;
                int grow = row0 + w * 32 + rt * 16 + q * 4 + reg;
                #pragma unroll
                for (int ct = 0; ct < 4; ct++) {
                    float s = fmaf(-2.f, acc[rt][ct][reg], e2v[ct]);
                    if (s < thr) {
                        int slot = atomicAdd(&gcount[grow], 1);
                        if (slot < CAP)
                            gcand[(size_t)grow * CAP + slot] = make_float2(s,
                                __int_as_float(kcol0 + ct * 16 + colb));
                    }
                }
            }
        }
    }

    // final per-quarter row minima
    #pragma unroll
    for (int r8 = 0; r8 < 8; r8++) {
        float gm = row16_min(m[r8]);
        if (colb == 0) {
            int grow = row0 + w * 32 + (r8 >> 2) * 16 + q * 4 + (r8 & 3);
            growmin[grow * 4 + quarter] = gm;
        }
    }
}

// ---------------- resolve winners (exact fp32 chain, proven R2-R9) ----------------
// grid 512 x 256 thr: 4 waves x 16 rows.
__global__ __launch_bounds__(256) void vq_resolve(const float* __restrict__ z,
                                                  const float* __restrict__ emb,
                                                  const float* __restrict__ e2np,
                                                  const float* __restrict__ z2np,
                                                  const float2* __restrict__ gcand,
                                                  const int* __restrict__ gcount,
                                                  const float* __restrict__ growmin,
                                                  float* __restrict__ out_idx) {
    const int t = threadIdx.x;
    const int l = t & 63;
    const int w = t >> 6;
    const int grow0 = blockIdx.x * 64 + w * 16;

    for (int rr = 0; rr < 16; rr++) {
        int grow = grow0 + rr;
        int c = gcount[grow];
        float thr = fminf(fminf(growmin[grow * 4], growmin[grow * 4 + 1]),
                          fminf(growmin[grow * 4 + 2], growmin[grow * 4 + 3])) + DELTA;
        int widx;
        if (c > CAP) {
            // exhaustive exact (practically never taken)
            float bs = 3.4e38f; int bk = 0x7fffffff;
            float z2r = z2np[grow];
            const float* zr = z + (size_t)grow * DIM;
            for (int k0 = l; k0 < K_EMB; k0 += 64) {
                const float* er = emb + (size_t)k0 * DIM;
                float accd = 0.f;
                for (int d = 0; d < DIM; d++) accd = fmaf(zr[d], er[d], accd);
                float s = __fsub_rn(__fadd_rn(z2r, e2np[k0]), __fmul_rn(2.f, accd));
                if (s < bs || (s == bs && k0 < bk)) { bs = s; bk = k0; }
            }
            #pragma unroll
            for (int off = 32; off; off >>= 1) {
                float os = __shfl_xor(bs, off, 64);
                int   ok = __shfl_xor(bk, off, 64);
                if (os < bs || (os == bs && ok < bk)) { bs = os; bk = ok; }
            }
            widx = bk;
        } else {
            float cs = 3.4e38f; int ck = 0x7fffffff; bool eff = false;
            if (l < c) {
                float2 cd = gcand[(size_t)grow * CAP + l];
                if (cd.x < thr) { eff = true; ck = __float_as_int(cd.y); }
            }
            unsigned long long ball = __ballot(eff);
            int ne = __popcll(ball);
            if (ne == 1) {
                int src = __ffsll(ball) - 1;
                widx = __shfl(ck, src, 64);
            } else {
                if (eff) {
                    const float* zr = z + (size_t)grow * DIM;
                    const float* er = emb + (size_t)ck * DIM;
                    float accd = 0.f;
                    for (int d = 0; d < DIM; d++) accd = fmaf(zr[d], er[d], accd);
                    cs = __fsub_rn(__fadd_rn(z2np[grow], e2np[ck]), __fmul_rn(2.f, accd));
                }
                float bs = cs; int bk = ck;
                #pragma unroll
                for (int off = 32; off; off >>= 1) {
                    float os = __shfl_xor(bs, off, 64);
                    int   ok = __shfl_xor(bk, off, 64);
                    if (os < bs || (os == bs && ok < bk)) { bs = os; bk = ok; }
                }
                widx = bk;
            }
        }
        if (l == 0) out_idx[grow] = (float)widx;
    }
}

// ---------------- gather z_q + loss partials ----------------
__global__ __launch_bounds__(256) void vq_gather(const float* __restrict__ z,
                                                 const float* __restrict__ emb,
                                                 const float* __restrict__ out_idx,
                                                 float* __restrict__ out_zq,
                                                 double* __restrict__ partial) {
    __shared__ double Wsum[4];
    const int t = threadIdx.x;
    const int row0 = blockIdx.x * 128;
    double lsum;
    {
        int row = t >> 1;
        int d0  = (t & 1) * 128;
        int gi  = (int)out_idx[row0 + row];
        const float4* ev = (const float4*)(emb + (size_t)gi * DIM + d0);
        const float4* zv = (const float4*)(z + (size_t)(row0 + row) * DIM + d0);
        float4*       ov = (float4*)(out_zq + (size_t)(row0 + row) * DIM + d0);
        float fs = 0.f;
        #pragma unroll 8
        for (int q = 0; q < 32; q++) {
            float4 e = ev[q];
            float4 zz = zv[q];
            ov[q] = e;
            float dx = e.x - zz.x, dy = e.y - zz.y, dz = e.z - zz.z, dw = e.w - zz.w;
            fs += dx * dx + dy * dy + dz * dz + dw * dw;
        }
        lsum = (double)fs;
    }
    #pragma unroll
    for (int off = 32; off; off >>= 1) lsum += __shfl_down(lsum, off, 64);
    if ((t & 63) == 0) Wsum[t >> 6] = lsum;
    __syncthreads();
    if (t == 0) partial[blockIdx.x] = Wsum[0] + Wsum[1] + Wsum[2] + Wsum[3];
}

// ---------------- finalize: parallel fp64 reduce of 256 partials ----------------
__global__ __launch_bounds__(256) void finalize(const double* __restrict__ partial,
                                                float* __restrict__ out_loss) {
    __shared__ double W[4];
    const int t = threadIdx.x;
    double s = partial[t];
    #pragma unroll
    for (int off = 32; off; off >>= 1) s += __shfl_down(s, off, 64);
    if ((t & 63) == 0) W[t >> 6] = s;
    __syncthreads();
    if (t == 0)
        out_loss[0] = (float)(1.25 * (W[0] + W[1] + W[2] + W[3]) / (double)OUT_ZQ_SIZE);
}

extern "C" void kernel_launch(void* const* d_in, const int* in_sizes, int n_in,
                              void* d_out, int out_size, void* d_ws, size_t ws_size,
                              hipStream_t stream) {
    const float* z   = (const float*)d_in[0];
    const float* emb = (const float*)d_in[1];
    float* out      = (float*)d_out;
    float* out_zq   = out;
    float* out_loss = out + OUT_ZQ_SIZE;
    float* out_idx  = out + OUT_ZQ_SIZE + 1;

    float*  e2np    = (float*)d_ws;                            // 8KB
    float*  z2np    = (float*)((char*)d_ws + 8192);            // 128KB
    double* partial = (double*)((char*)d_ws + 8192 + 131072);  // 2KB

    // carves from d_out's z_q region (rewritten by vq_gather at the end):
    //   [0,1MB)        eb      bf16 embedding
    //   [1MB,17MB)     zb      bf16 z
    //   [17MB,25MB)    gcand   [32768][32] float2
    //   [25MB,+128K)   gcount  [32768] int
    //   [+128K,+640K)  growmin [32768][4] float
    unsigned short* eb   = (unsigned short*)d_out;
    unsigned short* zb   = (unsigned short*)((char*)d_out + (1u << 20));
    float2*         gcnd = (float2*)((char*)d_out + (17u << 20));
    int*            gcnt = (int*)((char*)d_out + (25u << 20));
    float*          grmn = (float*)((char*)d_out + (25u << 20) + 131072);

    hipMemsetAsync(gcnt, 0, N_ROWS * sizeof(int), stream);
    hipLaunchKernelGGL(prep,       dim3(256),  dim3(256), 0, stream, emb, eb, e2np);
    hipLaunchKernelGGL(prep,       dim3(4096), dim3(256), 0, stream, z,   zb, z2np);
    hipLaunchKernelGGL(vq_mfma,    dim3(1024), dim3(256), 0, stream,
                       zb, eb, e2np, gcnd, gcnt, grmn);
    hipLaunchKernelGGL(vq_resolve, dim3(512),  dim3(256), 0, stream,
                       z, emb, e2np, z2np, gcnd, gcnt, grmn, out_idx);
    hipLaunchKernelGGL(vq_gather,  dim3(256),  dim3(256), 0, stream,
                       z, emb, out_idx, out_zq, partial);
    hipLaunchKernelGGL(finalize,   dim3(1),    dim3(256), 0, stream, partial, out_loss);
}

// Round 11
// 235.988 us; speedup vs baseline: 1.0857x; 1.0857x over previous
//
#include <hip/hip_runtime.h>

#define N_ROWS 32768
#define DIM    256
#define K_EMB  2048
#define OUT_ZQ_SIZE (N_ROWS * DIM)
#define DELTA  4e-4f
#define CAP    32

typedef short s16x8 __attribute__((ext_vector_type(8)));
typedef float f32x4 __attribute__((ext_vector_type(4)));

// min across each 16-lane DPP row via row_ror 8,4,2,1
__device__ inline float row16_min(float x) {
    int v = __builtin_amdgcn_update_dpp(0, __float_as_int(x), 0x128, 0xf, 0xf, false);
    x = fminf(x, __int_as_float(v));
    v = __builtin_amdgcn_update_dpp(0, __float_as_int(x), 0x124, 0xf, 0xf, false);
    x = fminf(x, __int_as_float(v));
    v = __builtin_amdgcn_update_dpp(0, __float_as_int(x), 0x122, 0xf, 0xf, false);
    x = fminf(x, __int_as_float(v));
    v = __builtin_amdgcn_update_dpp(0, __float_as_int(x), 0x121, 0xf, 0xf, false);
    x = fminf(x, __int_as_float(v));
    return x;
}

// ---------------- fused: f32 -> bf16 (RNE) + numpy-pairwise row sumsq ----------------
// blocks 0..255 -> embedding; blocks 256..4351 -> z.
__global__ __launch_bounds__(256) void prep(const float* __restrict__ z,
                                            const float* __restrict__ emb,
                                            unsigned short* __restrict__ zb,
                                            unsigned short* __restrict__ eb,
                                            float* __restrict__ z2,
                                            float* __restrict__ e2) {
    const int t = threadIdx.x;
    int nb = blockIdx.x;
    const float* src;
    unsigned short* dstb;
    float* dst2;
    if (nb < 256) { src = emb; dstb = eb; dst2 = e2; }
    else          { src = z;   dstb = zb; dst2 = z2; nb -= 256; }
    {
        size_t e0 = (size_t)nb * 2048 + (size_t)t * 8;
        const float4* s = (const float4*)(src + e0);
        float4 v0 = s[0], v1 = s[1];
        float f[8] = {v0.x, v0.y, v0.z, v0.w, v1.x, v1.y, v1.z, v1.w};
        unsigned int r[8];
        #pragma unroll
        for (int j = 0; j < 8; j++) {
            unsigned int u = __float_as_uint(f[j]);
            r[j] = (u + 0x7fffu + ((u >> 16) & 1u)) >> 16;
        }
        uint4 o;
        o.x = r[0] | (r[1] << 16);
        o.y = r[2] | (r[3] << 16);
        o.z = r[4] | (r[5] << 16);
        o.w = r[6] | (r[7] << 16);
        *(uint4*)(dstb + e0) = o;
    }
    if (t < 128) {
        int row = nb * 8 + (t >> 4);
        int lane = t & 15;
        const float* p = src + (size_t)row * DIM;
        int base = (lane >> 3) * 128 + (lane & 7);
        float r = __fmul_rn(p[base], p[base]);
        #pragma unroll
        for (int i = 1; i < 16; i++) {
            float v = p[base + 8 * i];
            r = __fadd_rn(r, __fmul_rn(v, v));
        }
        r = __fadd_rn(r, __shfl_xor(r, 1, 64));
        r = __fadd_rn(r, __shfl_xor(r, 2, 64));
        r = __fadd_rn(r, __shfl_xor(r, 4, 64));
        r = __fadd_rn(r, __shfl_xor(r, 8, 64));
        if (lane == 0) dst2[row] = r;
    }
}

// ---------------- MFMA screen (quarter-split, XCD-swizzled, conflict-free LDS) --------
// grid 1024 = 256 row-tiles x 4 col-quarters, XCD-bijective mapping so the 4
// quarters of a tile share one XCD's L2 (zb fetched from HBM once).
// Block: 128 rows x 512 cols, 4 waves (wave w: rows w*32..+31, rt=2, ct=4).
// LDS: 2 x 16KB dbuf, layout [dhalf(2)][col(64)][128B] with full (col&7)<<4 XOR
// (lrow&7 == col&7 -> conflict-free 16-lane phases, as measured in R9).
__global__ __launch_bounds__(256, 4) void vq_mfma(const unsigned short* __restrict__ zb,
                                                  const unsigned short* __restrict__ eb,
                                                  const float* __restrict__ e2np,
                                                  float2* __restrict__ gcand,
                                                  int* __restrict__ gcount,
                                                  float* __restrict__ growmin) {
    __shared__ __attribute__((aligned(16))) unsigned short Bs[2][8192];  // 2 x 16KB

    const int t = threadIdx.x;
    const int l = t & 63;
    const int w = t >> 6;
    // XCD-bijective swizzle: b = (tile%8) + 8*((tile>>3)*4 + quarter)
    const int b = blockIdx.x;
    const int kk_ = b >> 3;
    const int quarter = kk_ & 3;
    const int tile = (kk_ >> 2) * 8 + (b & 7);
    const int row0 = tile * 128;
    const int col0 = quarter * 512;
    const int colb = l & 15;
    const int q    = l >> 4;
    const int hi16 = q << 4;
    const int swz  = (colb & 7) << 4;

    // A fragments: rows row0 + w*32 + rt*16 + colb; d = ak*32 + q*8
    s16x8 a[2][8];
    {
        const unsigned short* zbase = zb + (size_t)(row0 + w * 32) * DIM;
        #pragma unroll
        for (int rt = 0; rt < 2; rt++)
            #pragma unroll
            for (int kf = 0; kf < 8; kf++)
                a[rt][kf] = *(const s16x8*)(zbase + (rt * 16 + colb) * DIM + kf * 32 + q * 8);
    }

    // stage one 64col x 128D chunk (16KB) into Bs[buf].
    // LDS row lrow = dhalf*64 + col (128B each); source pre-swizzled by (lrow&7)<<4.
    auto stage = [&](int buf, int kc0, int dc) {
        char* lbase = (char*)&Bs[buf][0];
        #pragma unroll
        for (int i = 0; i < 4; i++) {
            int s    = (w * 4 + i) * 64 + l;   // 16B slot 0..1023
            int lrow = s >> 3;                 // 8 slots per 128B row
            int kk   = (s & 7) << 4;           // byte 0..112
            int ss   = kk ^ ((lrow & 7) << 4);
            int col  = lrow & 63;
            int dh   = lrow >> 6;
            const char* gsrc = (const char*)eb + (size_t)(kc0 + col) * 512
                               + dc * 256 + dh * 128 + ss;
            char* ldst = lbase + (w * 4 + i) * 1024;   // wave-uniform base (+ lane*16 by HW)
            __builtin_amdgcn_global_load_lds(
                (const __attribute__((address_space(1))) unsigned int*)gsrc,
                (__attribute__((address_space(3))) unsigned int*)ldst,
                16, 0, 0);
        }
    };

    float m[8];
    #pragma unroll
    for (int i = 0; i < 8; i++) m[i] = 3.4e38f;

    stage(0, col0, 0);
    __syncthreads();

    f32x4 acc[2][4];

    for (int kt = 0; kt < 8; kt++) {
        const int kcol0 = col0 + kt * 64;

        float e2v[4];
        #pragma unroll
        for (int ct = 0; ct < 4; ct++) e2v[ct] = e2np[kcol0 + ct * 16 + colb];

        #pragma unroll
        for (int rt = 0; rt < 2; rt++)
            #pragma unroll
            for (int ct = 0; ct < 4; ct++)
                acc[rt][ct] = (f32x4){0.f, 0.f, 0.f, 0.f};

        #pragma unroll
        for (int dc = 0; dc < 2; dc++) {
            const int p = kt * 2 + dc;
            const int cur = p & 1;
            if (p < 15) {
                const int pn = p + 1;
                stage(cur ^ 1, col0 + (pn >> 1) * 64, pn & 1);
            }
            const char* rbase = (const char*)&Bs[cur][0];
            #pragma unroll
            for (int kf2 = 0; kf2 < 4; kf2++) {
                const int dh    = kf2 >> 1;
                const int inner = ((kf2 & 1) * 64 + hi16) ^ swz;
                const int ak    = dc * 4 + kf2;
                #pragma unroll
                for (int ct = 0; ct < 4; ct++) {
                    s16x8 bfr = *(const s16x8*)(rbase + dh * 8192
                                 + (ct * 16 + colb) * 128 + inner);
                    acc[0][ct] = __builtin_amdgcn_mfma_f32_16x16x32_bf16(a[0][ak], bfr, acc[0][ct], 0, 0, 0);
                    acc[1][ct] = __builtin_amdgcn_mfma_f32_16x16x32_bf16(a[1][ak], bfr, acc[1][ct], 0, 0, 0);
                }
            }
            __syncthreads();   // drains prefetch; protects Bs[cur] overwrite
        }

        // epilogue: s = e2 - 2*dot ; tile-min; running min; push window to GLOBAL
        float tmin[8];
        #pragma unroll
        for (int rt = 0; rt < 2; rt++)
            #pragma unroll
            for (int reg = 0; reg < 4; reg++) {
                int r8 = rt * 4 + reg;
                float t0 = fmaf(-2.f, acc[rt][0][reg], e2v[0]);
                #pragma unroll
                for (int ct = 1; ct < 4; ct++)
                    t0 = fminf(t0, fmaf(-2.f, acc[rt][ct][reg], e2v[ct]));
                tmin[r8] = t0;
                m[r8] = fminf(m[r8], t0);
            }
        #pragma unroll
        for (int r8 = 0; r8 < 8; r8++) {
            float gm  = row16_min(m[r8]);
            float thr = gm + DELTA;
            if (tmin[r8] < thr) {
                int rt = r8 >> 2, reg = r8 & 3;
                int grow = row0 + w * 32 + rt * 16 + q * 4 + reg;
                #pragma unroll
                for (int ct = 0; ct < 4; ct++) {
                    float s = fmaf(-2.f, acc[rt][ct][reg], e2v[ct]);
                    if (s < thr) {
                        int slot = atomicAdd(&gcount[grow], 1);
                        if (slot < CAP)
                            gcand[(size_t)grow * CAP + slot] = make_float2(s,
                                __int_as_float(kcol0 + ct * 16 + colb));
                    }
                }
            }
        }
    }

    // final per-quarter row minima
    #pragma unroll
    for (int r8 = 0; r8 < 8; r8++) {
        float gm = row16_min(m[r8]);
        if (colb == 0) {
            int grow = row0 + w * 32 + (r8 >> 2) * 16 + q * 4 + (r8 & 3);
            growmin[grow * 4 + quarter] = gm;
        }
    }
}

// ---------------- resolve winners (exact fp32 chain, proven R2-R10) ----------------
// grid 512 x 256 thr: 4 waves x 16 rows.
__global__ __launch_bounds__(256) void vq_resolve(const float* __restrict__ z,
                                                  const float* __restrict__ emb,
                                                  const float* __restrict__ e2np,
                                                  const float* __restrict__ z2np,
                                                  const float2* __restrict__ gcand,
                                                  const int* __restrict__ gcount,
                                                  const float* __restrict__ growmin,
                                                  float* __restrict__ out_idx) {
    const int t = threadIdx.x;
    const int l = t & 63;
    const int w = t >> 6;
    const int grow0 = blockIdx.x * 64 + w * 16;

    for (int rr = 0; rr < 16; rr++) {
        int grow = grow0 + rr;
        int c = gcount[grow];
        float thr = fminf(fminf(growmin[grow * 4], growmin[grow * 4 + 1]),
                          fminf(growmin[grow * 4 + 2], growmin[grow * 4 + 3])) + DELTA;
        int widx;
        if (c > CAP) {
            // exhaustive exact (practically never taken)
            float bs = 3.4e38f; int bk = 0x7fffffff;
            float z2r = z2np[grow];
            const float* zr = z + (size_t)grow * DIM;
            for (int k0 = l; k0 < K_EMB; k0 += 64) {
                const float* er = emb + (size_t)k0 * DIM;
                float accd = 0.f;
                for (int d = 0; d < DIM; d++) accd = fmaf(zr[d], er[d], accd);
                float s = __fsub_rn(__fadd_rn(z2r, e2np[k0]), __fmul_rn(2.f, accd));
                if (s < bs || (s == bs && k0 < bk)) { bs = s; bk = k0; }
            }
            #pragma unroll
            for (int off = 32; off; off >>= 1) {
                float os = __shfl_xor(bs, off, 64);
                int   ok = __shfl_xor(bk, off, 64);
                if (os < bs || (os == bs && ok < bk)) { bs = os; bk = ok; }
            }
            widx = bk;
        } else {
            float cs = 3.4e38f; int ck = 0x7fffffff; bool eff = false;
            if (l < c) {
                float2 cd = gcand[(size_t)grow * CAP + l];
                if (cd.x < thr) { eff = true; ck = __float_as_int(cd.y); }
            }
            unsigned long long ball = __ballot(eff);
            int ne = __popcll(ball);
            if (ne == 1) {
                int src = __ffsll(ball) - 1;
                widx = __shfl(ck, src, 64);
            } else {
                if (eff) {
                    const float* zr = z + (size_t)grow * DIM;
                    const float* er = emb + (size_t)ck * DIM;
                    float accd = 0.f;
                    for (int d = 0; d < DIM; d++) accd = fmaf(zr[d], er[d], accd);
                    cs = __fsub_rn(__fadd_rn(z2np[grow], e2np[ck]), __fmul_rn(2.f, accd));
                }
                float bs = cs; int bk = ck;
                #pragma unroll
                for (int off = 32; off; off >>= 1) {
                    float os = __shfl_xor(bs, off, 64);
                    int   ok = __shfl_xor(bk, off, 64);
                    if (os < bs || (os == bs && ok < bk)) { bs = os; bk = ok; }
                }
                widx = bk;
            }
        }
        if (l == 0) out_idx[grow] = (float)widx;
    }
}

// ---------------- gather z_q + loss partials ----------------
__global__ __launch_bounds__(256) void vq_gather(const float* __restrict__ z,
                                                 const float* __restrict__ emb,
                                                 const float* __restrict__ out_idx,
                                                 float* __restrict__ out_zq,
                                                 double* __restrict__ partial) {
    __shared__ double Wsum[4];
    const int t = threadIdx.x;
    const int row0 = blockIdx.x * 128;
    double lsum;
    {
        int row = t >> 1;
        int d0  = (t & 1) * 128;
        int gi  = (int)out_idx[row0 + row];
        const float4* ev = (const float4*)(emb + (size_t)gi * DIM + d0);
        const float4* zv = (const float4*)(z + (size_t)(row0 + row) * DIM + d0);
        float4*       ov = (float4*)(out_zq + (size_t)(row0 + row) * DIM + d0);
        float fs = 0.f;
        #pragma unroll 8
        for (int q = 0; q < 32; q++) {
            float4 e = ev[q];
            float4 zz = zv[q];
            ov[q] = e;
            float dx = e.x - zz.x, dy = e.y - zz.y, dz = e.z - zz.z, dw = e.w - zz.w;
            fs += dx * dx + dy * dy + dz * dz + dw * dw;
        }
        lsum = (double)fs;
    }
    #pragma unroll
    for (int off = 32; off; off >>= 1) lsum += __shfl_down(lsum, off, 64);
    if ((t & 63) == 0) Wsum[t >> 6] = lsum;
    __syncthreads();
    if (t == 0) partial[blockIdx.x] = Wsum[0] + Wsum[1] + Wsum[2] + Wsum[3];
}

// ---------------- finalize: parallel fp64 reduce of 256 partials ----------------
__global__ __launch_bounds__(256) void finalize(const double* __restrict__ partial,
                                                float* __restrict__ out_loss) {
    __shared__ double W[4];
    const int t = threadIdx.x;
    double s = partial[t];
    #pragma unroll
    for (int off = 32; off; off >>= 1) s += __shfl_down(s, off, 64);
    if ((t & 63) == 0) W[t >> 6] = s;
    __syncthreads();
    if (t == 0)
        out_loss[0] = (float)(1.25 * (W[0] + W[1] + W[2] + W[3]) / (double)OUT_ZQ_SIZE);
}

extern "C" void kernel_launch(void* const* d_in, const int* in_sizes, int n_in,
                              void* d_out, int out_size, void* d_ws, size_t ws_size,
                              hipStream_t stream) {
    const float* z   = (const float*)d_in[0];
    const float* emb = (const float*)d_in[1];
    float* out      = (float*)d_out;
    float* out_zq   = out;
    float* out_loss = out + OUT_ZQ_SIZE;
    float* out_idx  = out + OUT_ZQ_SIZE + 1;

    float*  e2np    = (float*)d_ws;                            // 8KB
    float*  z2np    = (float*)((char*)d_ws + 8192);            // 128KB
    double* partial = (double*)((char*)d_ws + 8192 + 131072);  // 2KB

    // carves from d_out's z_q region (rewritten by vq_gather at the end):
    //   [0,1MB)        eb      bf16 embedding
    //   [1MB,17MB)     zb      bf16 z
    //   [17MB,25MB)    gcand   [32768][32] float2
    //   [25MB,+128K)   gcount  [32768] int
    //   [+128K,+640K)  growmin [32768][4] float
    unsigned short* eb   = (unsigned short*)d_out;
    unsigned short* zb   = (unsigned short*)((char*)d_out + (1u << 20));
    float2*         gcnd = (float2*)((char*)d_out + (17u << 20));
    int*            gcnt = (int*)((char*)d_out + (25u << 20));
    float*          grmn = (float*)((char*)d_out + (25u << 20) + 131072);

    hipMemsetAsync(gcnt, 0, N_ROWS * sizeof(int), stream);
    hipLaunchKernelGGL(prep,       dim3(4352), dim3(256), 0, stream,
                       z, emb, zb, eb, z2np, e2np);
    hipLaunchKernelGGL(vq_mfma,    dim3(1024), dim3(256), 0, stream,
                       zb, eb, e2np, gcnd, gcnt, grmn);
    hipLaunchKernelGGL(vq_resolve, dim3(512),  dim3(256), 0, stream,
                       z, emb, e2np, z2np, gcnd, gcnt, grmn, out_idx);
    hipLaunchKernelGGL(vq_gather,  dim3(256),  dim3(256), 0, stream,
                       z, emb, out_idx, out_zq, partial);
    hipLaunchKernelGGL(finalize,   dim3(1),    dim3(256), 0, stream, partial, out_loss);
}

// Round 12
// 202.865 us; speedup vs baseline: 1.2630x; 1.1633x over previous
//
#include <hip/hip_runtime.h>

#define N_ROWS 32768
#define DIM    256
#define K_EMB  2048
#define OUT_ZQ_SIZE (N_ROWS * DIM)
#define DELTA  4e-4f
#define CAP    16

typedef short s16x8 __attribute__((ext_vector_type(8)));
typedef float f32x4 __attribute__((ext_vector_type(4)));

// min across each 16-lane DPP row via row_ror 8,4,2,1
__device__ inline float row16_min(float x) {
    int v = __builtin_amdgcn_update_dpp(0, __float_as_int(x), 0x128, 0xf, 0xf, false);
    x = fminf(x, __int_as_float(v));
    v = __builtin_amdgcn_update_dpp(0, __float_as_int(x), 0x124, 0xf, 0xf, false);
    x = fminf(x, __int_as_float(v));
    v = __builtin_amdgcn_update_dpp(0, __float_as_int(x), 0x122, 0xf, 0xf, false);
    x = fminf(x, __int_as_float(v));
    v = __builtin_amdgcn_update_dpp(0, __float_as_int(x), 0x121, 0xf, 0xf, false);
    x = fminf(x, __int_as_float(v));
    return x;
}

// ---------------- fused: f32 -> bf16 (RNE) + numpy-pairwise row sumsq ----------------
// blocks 0..255 -> embedding; blocks 256..4351 -> z.  (proven R11)
__global__ __launch_bounds__(256) void prep(const float* __restrict__ z,
                                            const float* __restrict__ emb,
                                            unsigned short* __restrict__ zb,
                                            unsigned short* __restrict__ eb,
                                            float* __restrict__ z2,
                                            float* __restrict__ e2) {
    const int t = threadIdx.x;
    int nb = blockIdx.x;
    const float* src;
    unsigned short* dstb;
    float* dst2;
    if (nb < 256) { src = emb; dstb = eb; dst2 = e2; }
    else          { src = z;   dstb = zb; dst2 = z2; nb -= 256; }
    {
        size_t e0 = (size_t)nb * 2048 + (size_t)t * 8;
        const float4* s = (const float4*)(src + e0);
        float4 v0 = s[0], v1 = s[1];
        float f[8] = {v0.x, v0.y, v0.z, v0.w, v1.x, v1.y, v1.z, v1.w};
        unsigned int r[8];
        #pragma unroll
        for (int j = 0; j < 8; j++) {
            unsigned int u = __float_as_uint(f[j]);
            r[j] = (u + 0x7fffu + ((u >> 16) & 1u)) >> 16;
        }
        uint4 o;
        o.x = r[0] | (r[1] << 16);
        o.y = r[2] | (r[3] << 16);
        o.z = r[4] | (r[5] << 16);
        o.w = r[6] | (r[7] << 16);
        *(uint4*)(dstb + e0) = o;
    }
    if (t < 128) {
        int row = nb * 8 + (t >> 4);
        int lane = t & 15;
        const float* p = src + (size_t)row * DIM;
        int base = (lane >> 3) * 128 + (lane & 7);
        float r = __fmul_rn(p[base], p[base]);
        #pragma unroll
        for (int i = 1; i < 16; i++) {
            float v = p[base + 8 * i];
            r = __fadd_rn(r, __fmul_rn(v, v));
        }
        r = __fadd_rn(r, __shfl_xor(r, 1, 64));
        r = __fadd_rn(r, __shfl_xor(r, 2, 64));
        r = __fadd_rn(r, __shfl_xor(r, 4, 64));
        r = __fadd_rn(r, __shfl_xor(r, 8, 64));
        if (lane == 0) dst2[row] = r;
    }
}

// ---------------- MFMA screen (col-split halves, XCD-swizzled; R9 structure) ---------
// grid 512: tile = b & 255 (128 rows), half = b >> 8 (1024 cols).
// Both halves of a tile land on XCD tile%8 -> zb fetched from HBM once per XCD.
// 256 thr (4 waves); wave w: rows w*32..+31 (rt=2), 128-col kt tiles (ct=8).
// LDS: 2 x 16KB dbuf, 128B rows, XOR-swizzled (measured 0 conflicts in R9).
__global__ __launch_bounds__(256, 2) void vq_mfma(const unsigned short* __restrict__ zb,
                                                  const unsigned short* __restrict__ eb,
                                                  const float* __restrict__ e2np,
                                                  float2* __restrict__ gcand,
                                                  int* __restrict__ gcount,
                                                  float* __restrict__ growmin) {
    __shared__ __attribute__((aligned(16))) unsigned short Bs[2][8192];  // 2 x 16KB

    const int t = threadIdx.x;
    const int l = t & 63;
    const int w = t >> 6;
    const int b = blockIdx.x;
    const int tile = b & 255;          // XCD-bijective: XCD(tile,half) = tile % 8
    const int half = b >> 8;
    const int row0 = tile * 128;
    const int colb = l & 15;
    const int q    = l >> 4;
    const int hi16 = q << 4;
    const int swz  = (colb & 7) << 4;
    const int col0 = half * 1024;

    // A fragments: rows row0 + w*32 + rt*16 + colb; d = kf*32 + q*8
    s16x8 a[2][8];
    {
        const unsigned short* zbase = zb + (size_t)(row0 + w * 32) * DIM;
        #pragma unroll
        for (int rt = 0; rt < 2; rt++)
            #pragma unroll
            for (int kf = 0; kf < 8; kf++)
                a[rt][kf] = *(const s16x8*)(zbase + (rt * 16 + colb) * DIM + kf * 32 + q * 8);
    }

    // stage one 128col x 64D chunk (16KB) into Bs[buf]
    auto stage = [&](int buf, int kc0, int dc) {
        char* lbase = (char*)&Bs[buf][0];
        #pragma unroll
        for (int i = 0; i < 4; i++) {
            int s   = (w * 4 + i) * 64 + l;   // 16B slot 0..1023
            int col = s >> 3;                 // 8 slots per 128B col row
            int kk  = (s & 7) << 4;           // byte 0..112
            int ss  = kk ^ ((col & 7) << 4);
            const char* gsrc = (const char*)eb + (size_t)(kc0 + col) * 512 + dc * 128 + ss;
            char* ldst = lbase + (w * 4 + i) * 1024;   // wave-uniform base (+ lane*16 by HW)
            __builtin_amdgcn_global_load_lds(
                (const __attribute__((address_space(1))) unsigned int*)gsrc,
                (__attribute__((address_space(3))) unsigned int*)ldst,
                16, 0, 0);
        }
    };

    float m[8];
    #pragma unroll
    for (int i = 0; i < 8; i++) m[i] = 3.4e38f;

    stage(0, col0, 0);
    __syncthreads();

    f32x4 acc[2][8];

    for (int kt = 0; kt < 8; kt++) {
        const int kcol0 = col0 + kt * 128;

        float e2v[8];
        #pragma unroll
        for (int ct = 0; ct < 8; ct++) e2v[ct] = e2np[kcol0 + ct * 16 + colb];

        #pragma unroll
        for (int rt = 0; rt < 2; rt++)
            #pragma unroll
            for (int ct = 0; ct < 8; ct++)
                acc[rt][ct] = (f32x4){0.f, 0.f, 0.f, 0.f};

        #pragma unroll
        for (int dc = 0; dc < 4; dc++) {
            const int p = kt * 4 + dc;
            const int cur = p & 1;
            if (p < 31) {
                const int pn = p + 1;
                stage(cur ^ 1, col0 + (pn >> 2) * 128, pn & 3);
            }
            const char* rbase = (const char*)&Bs[cur][0];
            #pragma unroll
            for (int kf2 = 0; kf2 < 2; kf2++) {
                const int koff = (kf2 * 64 + hi16) ^ swz;
                const int ak   = dc * 2 + kf2;
                #pragma unroll
                for (int ct = 0; ct < 8; ct++) {
                    s16x8 bfr = *(const s16x8*)(rbase + (ct * 16 + colb) * 128 + koff);
                    acc[0][ct] = __builtin_amdgcn_mfma_f32_16x16x32_bf16(a[0][ak], bfr, acc[0][ct], 0, 0, 0);
                    acc[1][ct] = __builtin_amdgcn_mfma_f32_16x16x32_bf16(a[1][ak], bfr, acc[1][ct], 0, 0, 0);
                }
            }
            __syncthreads();   // drains prefetch; protects Bs[cur] overwrite
        }

        // epilogue: s = e2 - 2*dot ; tile-min; running min; push window to GLOBAL
        float tmin[8];
        #pragma unroll
        for (int rt = 0; rt < 2; rt++)
            #pragma unroll
            for (int reg = 0; reg < 4; reg++) {
                int r8 = rt * 4 + reg;
                float t0 = fmaf(-2.f, acc[rt][0][reg], e2v[0]);
                #pragma unroll
                for (int ct = 1; ct < 8; ct++)
                    t0 = fminf(t0, fmaf(-2.f, acc[rt][ct][reg], e2v[ct]));
                tmin[r8] = t0;
                m[r8] = fminf(m[r8], t0);
            }
        #pragma unroll
        for (int r8 = 0; r8 < 8; r8++) {
            float gm  = row16_min(m[r8]);
            float thr = gm + DELTA;
            if (tmin[r8] < thr) {
                int rt = r8 >> 2, reg = r8 & 3;
                int grow = row0 + w * 32 + rt * 16 + q * 4 + reg;
                #pragma unroll
                for (int ct = 0; ct < 8; ct++) {
                    float s = fmaf(-2.f, acc[rt][ct][reg], e2v[ct]);
                    if (s < thr) {
                        int slot = atomicAdd(&gcount[grow], 1);
                        if (slot < CAP)
                            gcand[(size_t)grow * CAP + slot] = make_float2(s,
                                __int_as_float(kcol0 + ct * 16 + colb));
                    }
                }
            }
        }
    }

    // final per-half row minima
    #pragma unroll
    for (int r8 = 0; r8 < 8; r8++) {
        float gm = row16_min(m[r8]);
        if (colb == 0) {
            int grow = row0 + w * 32 + (r8 >> 2) * 16 + q * 4 + (r8 & 3);
            growmin[grow * 2 + half] = gm;
        }
    }
}

// ---------------- resolve winners (exact fp32 chain, proven R2-R11) ----------------
// grid 512 x 256 thr: 4 waves x 16 rows.
__global__ __launch_bounds__(256) void vq_resolve(const float* __restrict__ z,
                                                  const float* __restrict__ emb,
                                                  const float* __restrict__ e2np,
                                                  const float* __restrict__ z2np,
                                                  const float2* __restrict__ gcand,
                                                  const int* __restrict__ gcount,
                                                  const float* __restrict__ growmin,
                                                  float* __restrict__ out_idx) {
    const int t = threadIdx.x;
    const int l = t & 63;
    const int w = t >> 6;
    const int grow0 = blockIdx.x * 64 + w * 16;

    for (int rr = 0; rr < 16; rr++) {
        int grow = grow0 + rr;
        int c = gcount[grow];
        float thr = fminf(growmin[grow * 2], growmin[grow * 2 + 1]) + DELTA;
        int widx;
        if (c > CAP) {
            // exhaustive exact (practically never taken)
            float bs = 3.4e38f; int bk = 0x7fffffff;
            float z2r = z2np[grow];
            const float* zr = z + (size_t)grow * DIM;
            for (int k0 = l; k0 < K_EMB; k0 += 64) {
                const float* er = emb + (size_t)k0 * DIM;
                float accd = 0.f;
                for (int d = 0; d < DIM; d++) accd = fmaf(zr[d], er[d], accd);
                float s = __fsub_rn(__fadd_rn(z2r, e2np[k0]), __fmul_rn(2.f, accd));
                if (s < bs || (s == bs && k0 < bk)) { bs = s; bk = k0; }
            }
            #pragma unroll
            for (int off = 32; off; off >>= 1) {
                float os = __shfl_xor(bs, off, 64);
                int   ok = __shfl_xor(bk, off, 64);
                if (os < bs || (os == bs && ok < bk)) { bs = os; bk = ok; }
            }
            widx = bk;
        } else {
            float cs = 3.4e38f; int ck = 0x7fffffff; bool eff = false;
            if (l < c) {
                float2 cd = gcand[(size_t)grow * CAP + l];
                if (cd.x < thr) { eff = true; ck = __float_as_int(cd.y); }
            }
            unsigned long long ball = __ballot(eff);
            int ne = __popcll(ball);
            if (ne == 1) {
                int src = __ffsll(ball) - 1;
                widx = __shfl(ck, src, 64);
            } else {
                if (eff) {
                    const float* zr = z + (size_t)grow * DIM;
                    const float* er = emb + (size_t)ck * DIM;
                    float accd = 0.f;
                    for (int d = 0; d < DIM; d++) accd = fmaf(zr[d], er[d], accd);
                    cs = __fsub_rn(__fadd_rn(z2np[grow], e2np[ck]), __fmul_rn(2.f, accd));
                }
                float bs = cs; int bk = ck;
                #pragma unroll
                for (int off = 32; off; off >>= 1) {
                    float os = __shfl_xor(bs, off, 64);
                    int   ok = __shfl_xor(bk, off, 64);
                    if (os < bs || (os == bs && ok < bk)) { bs = os; bk = ok; }
                }
                widx = bk;
            }
        }
        if (l == 0) out_idx[grow] = (float)widx;
    }
}

// ---------------- gather z_q + loss partials ----------------
__global__ __launch_bounds__(256) void vq_gather(const float* __restrict__ z,
                                                 const float* __restrict__ emb,
                                                 const float* __restrict__ out_idx,
                                                 float* __restrict__ out_zq,
                                                 double* __restrict__ partial) {
    __shared__ double Wsum[4];
    const int t = threadIdx.x;
    const int row0 = blockIdx.x * 128;
    double lsum;
    {
        int row = t >> 1;
        int d0  = (t & 1) * 128;
        int gi  = (int)out_idx[row0 + row];
        const float4* ev = (const float4*)(emb + (size_t)gi * DIM + d0);
        const float4* zv = (const float4*)(z + (size_t)(row0 + row) * DIM + d0);
        float4*       ov = (float4*)(out_zq + (size_t)(row0 + row) * DIM + d0);
        float fs = 0.f;
        #pragma unroll 8
        for (int q = 0; q < 32; q++) {
            float4 e = ev[q];
            float4 zz = zv[q];
            ov[q] = e;
            float dx = e.x - zz.x, dy = e.y - zz.y, dz = e.z - zz.z, dw = e.w - zz.w;
            fs += dx * dx + dy * dy + dz * dz + dw * dw;
        }
        lsum = (double)fs;
    }
    #pragma unroll
    for (int off = 32; off; off >>= 1) lsum += __shfl_down(lsum, off, 64);
    if ((t & 63) == 0) Wsum[t >> 6] = lsum;
    __syncthreads();
    if (t == 0) partial[blockIdx.x] = Wsum[0] + Wsum[1] + Wsum[2] + Wsum[3];
}

// ---------------- finalize: parallel fp64 reduce of 256 partials ----------------
__global__ __launch_bounds__(256) void finalize(const double* __restrict__ partial,
                                                float* __restrict__ out_loss) {
    __shared__ double W[4];
    const int t = threadIdx.x;
    double s = partial[t];
    #pragma unroll
    for (int off = 32; off; off >>= 1) s += __shfl_down(s, off, 64);
    if ((t & 63) == 0) W[t >> 6] = s;
    __syncthreads();
    if (t == 0)
        out_loss[0] = (float)(1.25 * (W[0] + W[1] + W[2] + W[3]) / (double)OUT_ZQ_SIZE);
}

extern "C" void kernel_launch(void* const* d_in, const int* in_sizes, int n_in,
                              void* d_out, int out_size, void* d_ws, size_t ws_size,
                              hipStream_t stream) {
    const float* z   = (const float*)d_in[0];
    const float* emb = (const float*)d_in[1];
    float* out      = (float*)d_out;
    float* out_zq   = out;
    float* out_loss = out + OUT_ZQ_SIZE;
    float* out_idx  = out + OUT_ZQ_SIZE + 1;

    float*  e2np    = (float*)d_ws;                            // 8KB
    float*  z2np    = (float*)((char*)d_ws + 8192);            // 128KB
    double* partial = (double*)((char*)d_ws + 8192 + 131072);  // 2KB

    // carves from d_out's z_q region (rewritten by vq_gather at the end):
    //   [0,1MB)        eb      bf16 embedding
    //   [1MB,17MB)     zb      bf16 z
    //   [17MB,21MB)    gcand   [32768][16] float2
    //   [21MB,+128K)   gcount  [32768] int
    //   [+128K,+384K)  growmin [32768][2] float
    unsigned short* eb   = (unsigned short*)d_out;
    unsigned short* zb   = (unsigned short*)((char*)d_out + (1u << 20));
    float2*         gcnd = (float2*)((char*)d_out + (17u << 20));
    int*            gcnt = (int*)((char*)d_out + (21u << 20));
    float*          grmn = (float*)((char*)d_out + (21u << 20) + 131072);

    hipMemsetAsync(gcnt, 0, N_ROWS * sizeof(int), stream);
    hipLaunchKernelGGL(prep,       dim3(4352), dim3(256), 0, stream,
                       z, emb, zb, eb, z2np, e2np);
    hipLaunchKernelGGL(vq_mfma,    dim3(512),  dim3(256), 0, stream,
                       zb, eb, e2np, gcnd, gcnt, grmn);
    hipLaunchKernelGGL(vq_resolve, dim3(512),  dim3(256), 0, stream,
                       z, emb, e2np, z2np, gcnd, gcnt, grmn, out_idx);
    hipLaunchKernelGGL(vq_gather,  dim3(256),  dim3(256), 0, stream,
                       z, emb, out_idx, out_zq, partial);
    hipLaunchKernelGGL(finalize,   dim3(1),    dim3(256), 0, stream, partial, out_loss);
}